// Round 13
// baseline (170.664 us; speedup 1.0000x reference)
//
#include <hip/hip_runtime.h>

// SVSAlgorithm: per-pixel sequential threshold recurrence over T frames,
// fused with 3x3 constant-kernel "DiffErosion" conv + relu epilogue.
//
// Two-launch design. Closed dead-ends (do NOT revisit): kernel-role fusion
// (R5/R8/R10: VGPR=60 collapse); float2 scan (R7/R11); cross-stage register
// prefetch in compute (R12: VGPR=32 collapse, +28us). Proven: scalar pinned
// scan ~50us (R9); per-slice compute ~89us (R11).
//  L1 svs_scan<64>: R9-proven verbatim. 80 blocks x 256 thr, 2x32 double-
//     buffered prefetch pinned with sched_barrier(0), launch_bounds(256,1).
//     Skips frames >= 1984 (never consumed). Snapshots every 64 frames.
//  L2 svs_compute2<64>: NEW GEOMETRY - 32x8 interior tiles ALIGNED to
//     32-col boundaries (160=5x32, 128=16x8) so every output row segment
//     is one aligned 128B line -> write amplification 1.0 by construction
//     (R9-R12 measured 210-248MB written vs 168 ideal with 14-wide tiles).
//     Block=384: phase A (340 thr) sigmoid for 34x10 halo tile, 1 px/thread;
//     phase B (256 thr) one output each: 9 LDS reads (3 colsums x 3), wave
//     spans 2 rows of 32 cols -> 2 lanes/bank = free. BUF=8 stages, 2
//     barriers/stage, no cross-stage prefetch. Sigmoid exp2(fma)+v_rcp;
//     state updates replicate reference f32 op order exactly; conv==box-sum
//     (all 9 weights equal; zero-pad of (1-hot) == hot=1 outside image).
//  ws ladder: SNAP=64 (5.08MB, known-good) -> SNAP=128 (2.4MB) -> 1-slice.

#define BUF 8        // frames per LDS stage in compute pass
#define PRE 32       // scan prefetch half-depth (double buffer)

constexpr int T_FRAMES = 2048;
constexpr int H_IMG = 128;
constexpr int W_IMG = 160;
constexpr int HW = H_IMG * W_IMG;
constexpr float C1 = 721.3475204444817f;         // 500 * log2(e)

constexpr size_t ws_needed(int snap) {
    return (size_t)(T_FRAMES / snap - 1) * HW * sizeof(float2);
}

// ---------------- L1: state-only scan (R9-proven, scalar, pinned) ---------
template <int SNAP_>
__global__ __launch_bounds__(256, 1)
void svs_scan(const float* __restrict__ x, const float* __restrict__ params,
              const float* __restrict__ HT0, const float* __restrict__ LT0,
              float2* __restrict__ snap)
{
    constexpr int TEFF_ = T_FRAMES - SNAP_;      // tail frames never consumed
    const int pix = (int)blockIdx.x * 256 + (int)threadIdx.x;  // 80 blocks
    const float dC = params[0];
    const float dO = params[1];

    float HT = HT0[pix];
    float LT = LT0[pix];
    const float* xp = x + pix;

    float va[PRE], vb[PRE];
    #pragma unroll
    for (int i = 0; i < PRE; ++i) va[i] = xp[i * HW];
    __builtin_amdgcn_sched_barrier(0);

    for (int t = 0; t < TEFF_; t += 2 * PRE) {
        #pragma unroll
        for (int i = 0; i < PRE; ++i) vb[i] = xp[(t + PRE + i) * HW];
        __builtin_amdgcn_sched_barrier(0);
        #pragma unroll
        for (int i = 0; i < PRE; ++i) {
            const float img = va[i];
            HT = ((img - HT) > 0.0f) ? (HT + dO) : (HT - dC);
            LT = ((LT - img) > 0.0f) ? (LT - dO) : (LT + dC);
        }
        if (((t + PRE) % SNAP_) == 0) {
            const int k = (t + PRE) / SNAP_ - 1;
            if (k >= 0 && k < T_FRAMES / SNAP_ - 1)
                snap[(size_t)k * HW + pix] = make_float2(HT, LT);
        }
        if (t + 2 * PRE < TEFF_) {
            #pragma unroll
            for (int i = 0; i < PRE; ++i) va[i] = xp[(t + 2 * PRE + i) * HW];
        }
        __builtin_amdgcn_sched_barrier(0);
        #pragma unroll
        for (int i = 0; i < PRE; ++i) {
            const float img = vb[i];
            HT = ((img - HT) > 0.0f) ? (HT + dO) : (HT - dC);
            LT = ((LT - img) > 0.0f) ? (LT - dO) : (LT + dC);
        }
        if (((t + 2 * PRE) % SNAP_) == 0) {
            const int k = (t + 2 * PRE) / SNAP_ - 1;
            if (k < T_FRAMES / SNAP_ - 1)
                snap[(size_t)k * HW + pix] = make_float2(HT, LT);
        }
    }
}

// ---------------- L2: aligned 32x8 tile compute ---------------------------
// Tile: interior 32 cols x 8 rows, halo 1 -> 34x10 = 340 sigmoid pixels.
// Block 384 threads: t<340 phase A (sigmoid), t<256 phase B (conv+store).
template <int SNAP_>
__global__ __launch_bounds__(384)
void svs_compute2(const float* __restrict__ x, const float* __restrict__ params,
                  const float* __restrict__ HT0, const float* __restrict__ LT0,
                  const float* __restrict__ kern, const float2* __restrict__ snap,
                  float* __restrict__ out)
{
    const int tc = (int)blockIdx.x;              // 0..4   (col tile)
    const int tr = (int)blockIdx.y;              // 0..15  (row tile)
    const int slice = (int)blockIdx.z;           // 0..NSLICE-1
    const int t0 = slice * SNAP_;
    const int t = (int)threadIdx.x;

    const float dC   = params[0];
    const float dO   = params[1];
    const float dHot = params[2];
    const float kw   = kern[4];        // all 9 weights equal (2/9)
    const float c0   = dHot * C1;      // exp2 arg = fma(a, -C1, c0)

    // phase A geometry: 340 threads, 1 halo-tile pixel each
    const bool tA = (t < 340);
    const int  ca = tA ? (t % 34) : 0;           // 0..33 (halo col)
    const int  lr = tA ? (t / 34) : 0;           // 0..9  (halo row)
    const int  gcol = tc * 32 + ca - 1;          // -1..160
    const int  grow = tr * 8 + lr - 1;           // -1..128
    const bool valid = tA & (gcol >= 0) & (gcol < W_IMG) & (grow >= 0) & (grow < H_IMG);
    const int  pix = min(max(grow, 0), H_IMG - 1) * W_IMG + min(max(gcol, 0), W_IMG - 1);
    const float* xp = x + pix;

    float HT = 0.0f, LT = 0.0f;
    if (tA) {
        if (slice == 0) {
            HT = valid ? HT0[pix] : 0.0f;
            LT = valid ? LT0[pix] : 0.0f;
        } else {
            const float2 s = snap[(size_t)(slice - 1) * HW + pix];
            HT = valid ? s.x : 0.0f;
            LT = valid ? s.y : 0.0f;
        }
    }

    // phase B geometry: 256 threads, 1 output column each
    const bool tB = (t < 256);
    const int  oc = t & 31;                      // 0..31 interior col
    const int  orow = t >> 5;                    // 0..7  interior row
    float* op = out + (size_t)(tr * 8 + orow) * W_IMG + (tc * 32 + oc);

    // sm[lr][frame][col]: lr stride = BUF*36 = 288 == 0 mod 32 banks; a
    // phase-B wave covers 2 output rows (same banks) -> 2-way max (free).
    __shared__ float sm[10][BUF][36];

    for (int tb = t0; tb < t0 + SNAP_; tb += BUF) {
        float v[BUF];
        if (tA) {
            #pragma unroll
            for (int i = 0; i < BUF; ++i) v[i] = xp[(tb + i) * HW];
        }
        __builtin_amdgcn_sched_barrier(0);
        if (tA) {
            #pragma unroll
            for (int i = 0; i < BUF; ++i) {
                const float img = v[i];
                const float aH = img - HT;
                const float eH = __builtin_amdgcn_exp2f(fmaf(aH, -C1, c0));
                const float hH = __builtin_amdgcn_rcpf(1.0f + eH);
                HT = (aH > 0.0f) ? (HT + dO) : (HT - dC);
                const float aL = LT - img;
                const float eL = __builtin_amdgcn_exp2f(fmaf(aL, -C1, c0));
                const float hL = __builtin_amdgcn_rcpf(1.0f + eL);
                LT = (aL > 0.0f) ? (LT - dO) : (LT + dC);
                sm[lr][i][ca] = valid ? (hH + hL) : 1.0f;
            }
        }
        __syncthreads();
        if (tB) {
            #pragma unroll
            for (int i = 0; i < BUF; ++i) {
                // vertical colsums over halo rows orow..orow+2, cols oc..oc+2
                const float cs0 = sm[orow][i][oc    ] + sm[orow + 1][i][oc    ] + sm[orow + 2][i][oc    ];
                const float cs1 = sm[orow][i][oc + 1] + sm[orow + 1][i][oc + 1] + sm[orow + 2][i][oc + 1];
                const float cs2 = sm[orow][i][oc + 2] + sm[orow + 1][i][oc + 2] + sm[orow + 2][i][oc + 2];
                const float S = cs0 + cs1 + cs2;
                float o = fmaf(S, kw, -1.0f);            // 1 - kw*(9-S) = kw*S - 1
                o = fmaxf(o, 0.0f);
                op[(size_t)(tb + i) * HW] = o;           // aligned 128B row lines
            }
        }
        __syncthreads();
    }
}

extern "C" void kernel_launch(void* const* d_in, const int* in_sizes, int n_in,
                              void* d_out, int out_size, void* d_ws, size_t ws_size,
                              hipStream_t stream) {
    const float* x      = (const float*)d_in[0];
    const float* params = (const float*)d_in[1];
    const float* HT0p   = (const float*)d_in[2];
    const float* LT0p   = (const float*)d_in[3];
    const float* kern   = (const float*)d_in[4];
    float* out = (float*)d_out;

    if (ws_size >= ws_needed(64)) {
        float2* snap = (float2*)d_ws;
        svs_scan<64><<<dim3(HW / 256), dim3(256), 0, stream>>>(x, params, HT0p, LT0p, snap);
        svs_compute2<64><<<dim3(5, 16, T_FRAMES / 64), dim3(384), 0, stream>>>(
            x, params, HT0p, LT0p, kern, snap, out);
    } else if (ws_size >= ws_needed(128)) {
        float2* snap = (float2*)d_ws;
        svs_scan<128><<<dim3(HW / 256), dim3(256), 0, stream>>>(x, params, HT0p, LT0p, snap);
        svs_compute2<128><<<dim3(5, 16, T_FRAMES / 128), dim3(384), 0, stream>>>(
            x, params, HT0p, LT0p, kern, snap, out);
    } else {
        svs_compute2<2048><<<dim3(5, 16, 1), dim3(384), 0, stream>>>(
            x, params, HT0p, LT0p, kern, (const float2*)d_ws, out);
    }
}